// Round 11
// baseline (214.308 us; speedup 1.0000x reference)
//
#include <hip/hip_runtime.h>
#include <math.h>

#define HH 4
#define GG 64
#define BDST 16            // dsts per bucket
#define BSH  4             // log2(BDST)
#define SLOT 768           // max edges per bucket (mean ~272, +30 sigma)
#define NPT  16            // edges cached per thread in bucket_scatter
#define HWORDS 3328        // >= NBK, multiple of 256
constexpr float NEG_SLOPE = 0.2f;
constexpr float GN_EPS = 1e-5f;

typedef __attribute__((ext_vector_type(8))) short bf16x8;
typedef __attribute__((ext_vector_type(4))) float f32x4;

__device__ __forceinline__ unsigned short f2bf_rne(float f) {
  unsigned u = __float_as_uint(f);
  u += 0x7fffu + ((u >> 16) & 1u);       // round-to-nearest-even
  return (unsigned short)(u >> 16);
}

// ---------------- pack Wl|Wr into MFMA B-fragment layout (bf16) ----------------
__global__ __launch_bounds__(256) void wpack(
    const float* __restrict__ Wl, const float* __restrict__ Wr,
    unsigned short* __restrict__ Bfrag) {
  int tid = blockIdx.x * 256 + threadIdx.x;       // 0 .. 64*64-1
  int f = tid >> 6, l = tid & 63;
  int m = f >> 5;                                  // 0=Wl 1=Wr
  int t = (f >> 2) & 7;                            // col-tile 0..7
  int ks = f & 3;                                  // k-subtile 0..3
  int col = t * 16 + (l & 15);
  int k0 = ks * 32 + (l >> 4) * 8;
  const float* W = m ? Wr : Wl;
  unsigned short* dst = Bfrag + ((size_t)f * 64 + l) * 8;
  #pragma unroll
  for (int j = 0; j < 8; ++j)
    dst[j] = f2bf_rne(W[(k0 + j) * 128 + col]);
}

// ---------------- MFMA GEMM: xlb(bf16) = x@Wl, xr(f32) = x@Wr ----------------
__global__ __launch_bounds__(256) void gemm_mfma(
    const float* __restrict__ x, const unsigned short* __restrict__ Bfrag,
    unsigned short* __restrict__ xlb, float* __restrict__ xr, int n) {
  const int wave = (blockIdx.x * 256 + threadIdx.x) >> 6;
  if (wave * 16 >= n) return;
  const int l = threadIdx.x & 63;
  const int arow = min(wave * 16 + (l & 15), n - 1);
  const float4* xrow = reinterpret_cast<const float4*>(x + (size_t)arow * 128);

  bf16x8 a[4];
  #pragma unroll
  for (int ks = 0; ks < 4; ++ks) {
    float4 lo = xrow[ks * 8 + (l >> 4) * 2];
    float4 hi = xrow[ks * 8 + (l >> 4) * 2 + 1];
    bf16x8 v;
    v[0] = (short)f2bf_rne(lo.x); v[1] = (short)f2bf_rne(lo.y);
    v[2] = (short)f2bf_rne(lo.z); v[3] = (short)f2bf_rne(lo.w);
    v[4] = (short)f2bf_rne(hi.x); v[5] = (short)f2bf_rne(hi.y);
    v[6] = (short)f2bf_rne(hi.z); v[7] = (short)f2bf_rne(hi.w);
    a[ks] = v;
  }

  const int r0 = wave * 16 + (l >> 4) * 4;        // C/D rows for this lane
  const int cb = l & 15;                          // C/D col within tile
  #pragma unroll
  for (int t = 0; t < 8; ++t) {
    f32x4 acc = {0.f, 0.f, 0.f, 0.f};
    #pragma unroll
    for (int ks = 0; ks < 4; ++ks) {
      const bf16x8* bp = reinterpret_cast<const bf16x8*>(
          Bfrag + ((size_t)((0 * 8 + t) * 4 + ks) * 64 + l) * 8);
      acc = __builtin_amdgcn_mfma_f32_16x16x32_bf16(a[ks], *bp, acc, 0, 0, 0);
    }
    #pragma unroll
    for (int j = 0; j < 4; ++j) {
      int r = r0 + j;
      if (r < n) xlb[(size_t)r * 128 + t * 16 + cb] = f2bf_rne(acc[j]);
    }
  }
  #pragma unroll
  for (int t = 0; t < 8; ++t) {
    f32x4 acc = {0.f, 0.f, 0.f, 0.f};
    #pragma unroll
    for (int ks = 0; ks < 4; ++ks) {
      const bf16x8* bp = reinterpret_cast<const bf16x8*>(
          Bfrag + ((size_t)((1 * 8 + t) * 4 + ks) * 64 + l) * 8);
      acc = __builtin_amdgcn_mfma_f32_16x16x32_bf16(a[ks], *bp, acc, 0, 0, 0);
    }
    #pragma unroll
    for (int j = 0; j < 4; ++j) {
      int r = r0 + j;
      if (r < n) xr[(size_t)r * 128 + t * 16 + cb] = acc[j];
    }
  }
}

// ---------------- bucket scatter: edges -> 16-dst buckets (packed words) ----------
// word = bucket(12) | ldst(4) | src(16); fixed SLOT capacity per bucket.
__global__ __launch_bounds__(256) void bucket_scatter(
    const int* __restrict__ ei, int* __restrict__ gcur,
    int* __restrict__ ebuf, int E, int E2, int nbk) {
  __shared__ int hist[HWORDS];
  const int t = threadIdx.x;
  for (int i = t; i < HWORDS; i += 256) hist[i] = 0;
  __syncthreads();
  unsigned wcache[NPT];
  const int base = blockIdx.x * (256 * NPT);
  #pragma unroll
  for (int i = 0; i < NPT; ++i) {
    int e = base + i * 256 + t;
    unsigned w = 0xFFFFFFFFu;
    if (e < E2) {
      int src, dst;
      if (e < E) { src = ei[e]; dst = ei[E + e]; }
      else       { src = e - E; dst = e - E; }
      w = ((unsigned)(dst >> BSH) << 20) | ((unsigned)(dst & (BDST - 1)) << 16)
          | (unsigned)src;
      atomicAdd(&hist[dst >> BSH], 1);
    }
    wcache[i] = w;
  }
  __syncthreads();
  for (int b = t; b < nbk; b += 256) {
    int c = hist[b];
    if (c) hist[b] = atomicAdd(&gcur[b], c);   // hist[b] := global base
  }
  __syncthreads();
  #pragma unroll
  for (int i = 0; i < NPT; ++i) {
    unsigned w = wcache[i];
    if (w == 0xFFFFFFFFu) continue;
    int b = w >> 20;
    int pos = atomicAdd(&hist[b], 1);
    if (pos < SLOT) ebuf[b * SLOT + pos] = (int)(w & 0xFFFFF);
  }
}

// ---------------- fused per-bucket: local CSR + softmax-aggregate + gn-stats -----
// block = bucket of 16 dsts; 4 waves x 4 dsts. Lane q=lane&31 owns channels
// 4q..4q+3 (head q>>3); halves (hf=lane>>5) process alternating edges.
__global__ __launch_bounds__(256) void fused_aggr(
    const int* __restrict__ gcur, const int* __restrict__ ebuf,
    const unsigned char* __restrict__ xb,   // xlb as bytes ([n] rows of 256B)
    const float* __restrict__ xr, const float* __restrict__ att,
    const float* __restrict__ bias, const int* __restrict__ batch,
    float* __restrict__ out, float* __restrict__ gsum,
    float* __restrict__ gsumsq, int* __restrict__ gcnt, int n) {
  __shared__ int eraw[SLOT];
  __shared__ int elist[SLOT + 16];
  __shared__ int ldeg[BDST];
  __shared__ int lrow[BDST + 1];
  __shared__ int lcur[BDST];
  const int b = blockIdx.x;
  const int t = threadIdx.x;
  const int cnt = min(gcur[b], SLOT);
  if (t < BDST) ldeg[t] = 0;
  __syncthreads();
  for (int i = t; i < cnt; i += 256) {
    int w = ebuf[b * SLOT + i];
    eraw[i] = w;
    atomicAdd(&ldeg[(w >> 16) & (BDST - 1)], 1);
  }
  __syncthreads();
  if (t < BDST) {                       // 16-lane exclusive scan (wave 0)
    int v = ldeg[t];
    int incl = v;
    #pragma unroll
    for (int d = 1; d < BDST; d <<= 1) {
      int u = __shfl_up(incl, d);
      if (t >= d) incl += u;
    }
    lrow[t] = incl - v;
    lcur[t] = incl - v;
    if (t == BDST - 1) lrow[BDST] = incl;
  }
  __syncthreads();
  for (int i = t; i < cnt; i += 256) {
    int w = eraw[i];
    int pos = atomicAdd(&lcur[(w >> 16) & (BDST - 1)], 1);
    elist[pos] = (w & 0xFFFF) << 8;     // src byte-offset into xlb
  }
  if (t < 16) elist[cnt + t] = 0;       // pad: safe row-0 offsets for over-reads
  __syncthreads();

  const int wv = t >> 6, lane = t & 63;
  const int q = lane & 31, hf = lane >> 5;
  const float4 at4 = *reinterpret_cast<const float4*>(att + q * 4);
  const float4 bi4 = *reinterpret_cast<const float4*>(bias + q * 4);
  float vs0 = 0.f, vs1 = 0.f, vs2 = 0.f, vs3 = 0.f;
  float vq0 = 0.f, vq1 = 0.f, vq2 = 0.f, vq3 = 0.f;
  int scnt = 0, curg = -1;

  #define LDE(st) (*reinterpret_cast<const uint2*>( \
      xb + (size_t)(unsigned)ep[2 * (st) + hf] + q * 8))
  #define STEP(V, ebase) { \
    float x0 = __uint_as_float((V).x << 16); \
    float x1 = __uint_as_float((V).x & 0xffff0000u); \
    float x2 = __uint_as_float((V).y << 16); \
    float x3 = __uint_as_float((V).y & 0xffff0000u); \
    float t0 = x0 + xr4.x; t0 = fmaxf(t0, NEG_SLOPE * t0); \
    float t1 = x1 + xr4.y; t1 = fmaxf(t1, NEG_SLOPE * t1); \
    float t2 = x2 + xr4.z; t2 = fmaxf(t2, NEG_SLOPE * t2); \
    float t3 = x3 + xr4.w; t3 = fmaxf(t3, NEG_SLOPE * t3); \
    float p = fmaf(t3, at4.w, fmaf(t2, at4.z, fmaf(t1, at4.y, t0 * at4.x))); \
    p += __shfl_xor(p, 1); \
    p += __shfl_xor(p, 2); \
    p += __shfl_xor(p, 4); \
    float w = ((ebase) + hf < deg) ? __expf(p) : 0.f; \
    s += w; \
    a0 = fmaf(w, x0, a0); a1 = fmaf(w, x1, a1); \
    a2 = fmaf(w, x2, a2); a3 = fmaf(w, x3, a3); }

  #define FLUSH { \
    if (hf == 0) { \
      float* gp = gsum + curg * 128 + q * 4; \
      float* gq = gsumsq + curg * 128 + q * 4; \
      atomicAdd(gp + 0, vs0); atomicAdd(gp + 1, vs1); \
      atomicAdd(gp + 2, vs2); atomicAdd(gp + 3, vs3); \
      atomicAdd(gq + 0, vq0); atomicAdd(gq + 1, vq1); \
      atomicAdd(gq + 2, vq2); atomicAdd(gq + 3, vq3); \
    } \
    if (lane == 0) atomicAdd(&gcnt[curg], scnt); \
    vs0 = vs1 = vs2 = vs3 = 0.f; vq0 = vq1 = vq2 = vq3 = 0.f; scnt = 0; }

  for (int j = 0; j < 4; ++j) {
    const int ldst = wv * 4 + j;
    const int node = b * BDST + ldst;
    if (node >= n) break;
    const float4 xr4 = *reinterpret_cast<const float4*>(xr + (size_t)node * 128 + q * 4);
    const int k0 = lrow[ldst];
    const int deg = lrow[ldst + 1] - k0;   // >= 1 (self-loop)
    const int* ep = elist + k0;

    uint2 V0 = LDE(0), V1 = LDE(1), V2 = LDE(2), V3 = LDE(3);
    float s = 0.f, a0 = 0.f, a1 = 0.f, a2 = 0.f, a3 = 0.f;
    const int S = (deg + 1) >> 1;         // steps (2 edges each)
    for (int i = 0; i < S; i += 2) {
      STEP(V0, 2 * i)
      STEP(V1, 2 * i + 2)
      V0 = V2; V1 = V3;
      if (2 * i + 8 < deg)  V2 = LDE(i + 4);
      if (2 * i + 10 < deg) V3 = LDE(i + 5);
    }
    // combine halves
    s  += __shfl_xor(s, 32);
    a0 += __shfl_xor(a0, 32);
    a1 += __shfl_xor(a1, 32);
    a2 += __shfl_xor(a2, 32);
    a3 += __shfl_xor(a3, 32);
    float inv = 1.f / (s + 1e-16f);
    float o0 = a0 * inv, o1 = a1 * inv, o2 = a2 * inv, o3 = a3 * inv;
    if (hf == 0)
      *reinterpret_cast<float4*>(out + (size_t)node * 128 + q * 4) =
          make_float4(o0, o1, o2, o3);
    int g = batch[node];
    if (g != curg) {
      if (curg >= 0) FLUSH
      curg = g;
    }
    float v0 = o0 + bi4.x, v1 = o1 + bi4.y, v2 = o2 + bi4.z, v3 = o3 + bi4.w;
    vs0 += v0; vs1 += v1; vs2 += v2; vs3 += v3;
    vq0 = fmaf(v0, v0, vq0); vq1 = fmaf(v1, v1, vq1);
    vq2 = fmaf(v2, v2, vq2); vq3 = fmaf(v3, v3, vq3);
    scnt++;
  }
  if (curg >= 0) FLUSH
  #undef FLUSH
  #undef STEP
  #undef LDE
}

// ---------------- fold GraphNorm into per-(g,c) scale K and shift S ----------------
__global__ __launch_bounds__(128) void gn_prep(
    const float* __restrict__ gsum, const float* __restrict__ gsumsq,
    const int* __restrict__ gcnt, const float* __restrict__ bias,
    const float* __restrict__ msc, const float* __restrict__ w,
    const float* __restrict__ b, float* __restrict__ K, float* __restrict__ S) {
  int g = blockIdx.x, c = threadIdx.x;
  float cnt = (float)max(gcnt[g], 1);
  float mean = gsum[g * 128 + c] / cnt;
  float a = msc[c];
  float var = gsumsq[g * 128 + c] / cnt - mean * mean * (2.f * a - a * a);
  float k = rsqrtf(var + GN_EPS) * w[c];
  K[g * 128 + c] = k;
  S[g * 128 + c] = (bias[c] - mean * a) * k + b[c];
}

// ---------------- normalize + ELU (in place on out) ----------------
__global__ __launch_bounds__(256) void gn_norm(
    float* __restrict__ out, const int* __restrict__ batch,
    const float* __restrict__ K, const float* __restrict__ S, int n) {
  long long i = (long long)blockIdx.x * 256 + threadIdx.x;
  if (i >= (long long)n * 128) return;
  int nid = (int)(i >> 7), c = (int)(i & 127);
  int g = batch[nid];
  float val = fmaf(out[i], K[g * 128 + c], S[g * 128 + c]);
  out[i] = (val > 0.f) ? val : (__expf(val) - 1.f);
}

extern "C" void kernel_launch(void* const* d_in, const int* in_sizes, int n_in,
                              void* d_out, int out_size, void* d_ws, size_t ws_size,
                              hipStream_t stream) {
  const float* x    = (const float*)d_in[0];
  const int*   ei   = (const int*)d_in[1];
  const int*   batch= (const int*)d_in[2];
  const float* Wl   = (const float*)d_in[3];
  const float* Wr   = (const float*)d_in[4];
  const float* att  = (const float*)d_in[5];
  const float* bias = (const float*)d_in[6];
  const float* gw   = (const float*)d_in[7];
  const float* gb   = (const float*)d_in[8];
  const float* gms  = (const float*)d_in[9];
  float* out = (float*)d_out;

  const int n  = in_sizes[0] / 128;
  const int E  = in_sizes[1] / 2;
  const int E2 = E + n;
  const int NBK = (n + BDST - 1) / BDST;

  // workspace layout (zero-init region first: gcur|gcnt|gsum|gsumsq)
  char* ws = (char*)d_ws;
  size_t off = 0;
  int*   gcur    = (int*)(ws + off); off += (size_t)((NBK + 63) & ~63) * 4;
  int*   gcnt    = (int*)(ws + off); off += GG * 4;
  float* gsum    = (float*)(ws + off); off += GG * 128 * 4;
  float* gsumsq  = (float*)(ws + off); off += GG * 128 * 4;
  size_t zero_bytes = off;
  int*   ebuf    = (int*)(ws + off); off += (size_t)NBK * SLOT * 4;
  unsigned short* xlb = (unsigned short*)(ws + off); off += (size_t)n * 128 * 2;
  float* xr      = (float*)(ws + off); off += (size_t)n * 128 * 4;
  unsigned short* Bfrag = (unsigned short*)(ws + off); off += 64 * 64 * 8 * 2;
  float* gK      = (float*)(ws + off); off += GG * 128 * 4;
  float* gS      = (float*)(ws + off); off += GG * 128 * 4;

  hipMemsetAsync(ws, 0, zero_bytes, stream);

  bucket_scatter<<<(E2 + 256 * NPT - 1) / (256 * NPT), 256, 0, stream>>>(
      ei, gcur, ebuf, E, E2, NBK);

  wpack<<<16, 256, 0, stream>>>(Wl, Wr, (unsigned short*)Bfrag);
  {
    int waves = (n + 15) / 16;
    int blocks = (waves * 64 + 255) / 256;
    gemm_mfma<<<blocks, 256, 0, stream>>>(x, Bfrag, xlb, xr, n);
  }

  fused_aggr<<<NBK, 256, 0, stream>>>(gcur, ebuf, (const unsigned char*)xlb,
                                      xr, att, bias, batch, out,
                                      gsum, gsumsq, gcnt, n);

  gn_prep<<<GG, 128, 0, stream>>>(gsum, gsumsq, gcnt, bias, gms, gw, gb, gK, gS);

  long long t_nm = (long long)n * 128;
  gn_norm<<<(int)((t_nm + 255) / 256), 256, 0, stream>>>(out, batch, gK, gS, n);
}

// Round 12
// 130.832 us; speedup vs baseline: 1.6380x; 1.6380x over previous
//
#include <hip/hip_runtime.h>
#include <math.h>

#define HH 4
#define GG 64
#define CHUNK 64
#define BDST 16            // dsts per bucket
#define BSH  4             // log2(BDST)
#define SLOT 768           // max edges per bucket (mean ~272, +30 sigma)
#define NPT  16            // edges cached per thread in bucket_scatter
#define HWORDS 3328        // >= NBK, multiple of 256
constexpr float NEG_SLOPE = 0.2f;
constexpr float GN_EPS = 1e-5f;

typedef __attribute__((ext_vector_type(8))) short bf16x8;
typedef __attribute__((ext_vector_type(4))) float f32x4;

__device__ __forceinline__ unsigned short f2bf_rne(float f) {
  unsigned u = __float_as_uint(f);
  u += 0x7fffu + ((u >> 16) & 1u);       // round-to-nearest-even
  return (unsigned short)(u >> 16);
}

// ---------------- pack Wl|Wr into MFMA B-fragment layout (bf16) ----------------
__global__ __launch_bounds__(256) void wpack(
    const float* __restrict__ Wl, const float* __restrict__ Wr,
    unsigned short* __restrict__ Bfrag) {
  int tid = blockIdx.x * 256 + threadIdx.x;       // 0 .. 64*64-1
  int f = tid >> 6, l = tid & 63;
  int m = f >> 5;                                  // 0=Wl 1=Wr
  int t = (f >> 2) & 7;                            // col-tile 0..7
  int ks = f & 3;                                  // k-subtile 0..3
  int col = t * 16 + (l & 15);
  int k0 = ks * 32 + (l >> 4) * 8;
  const float* W = m ? Wr : Wl;
  unsigned short* dst = Bfrag + ((size_t)f * 64 + l) * 8;
  #pragma unroll
  for (int j = 0; j < 8; ++j)
    dst[j] = f2bf_rne(W[(k0 + j) * 128 + col]);
}

// ---------------- MFMA GEMM: xlb(bf16) = x@Wl, xr(f32) = x@Wr ----------------
__global__ __launch_bounds__(256) void gemm_mfma(
    const float* __restrict__ x, const unsigned short* __restrict__ Bfrag,
    unsigned short* __restrict__ xlb, float* __restrict__ xr, int n) {
  const int wave = (blockIdx.x * 256 + threadIdx.x) >> 6;
  if (wave * 16 >= n) return;
  const int l = threadIdx.x & 63;
  const int arow = min(wave * 16 + (l & 15), n - 1);
  const float4* xrow = reinterpret_cast<const float4*>(x + (size_t)arow * 128);

  bf16x8 a[4];
  #pragma unroll
  for (int ks = 0; ks < 4; ++ks) {
    float4 lo = xrow[ks * 8 + (l >> 4) * 2];
    float4 hi = xrow[ks * 8 + (l >> 4) * 2 + 1];
    bf16x8 v;
    v[0] = (short)f2bf_rne(lo.x); v[1] = (short)f2bf_rne(lo.y);
    v[2] = (short)f2bf_rne(lo.z); v[3] = (short)f2bf_rne(lo.w);
    v[4] = (short)f2bf_rne(hi.x); v[5] = (short)f2bf_rne(hi.y);
    v[6] = (short)f2bf_rne(hi.z); v[7] = (short)f2bf_rne(hi.w);
    a[ks] = v;
  }

  const int r0 = wave * 16 + (l >> 4) * 4;        // C/D rows for this lane
  const int cb = l & 15;                          // C/D col within tile
  #pragma unroll
  for (int t = 0; t < 8; ++t) {
    f32x4 acc = {0.f, 0.f, 0.f, 0.f};
    #pragma unroll
    for (int ks = 0; ks < 4; ++ks) {
      const bf16x8* bp = reinterpret_cast<const bf16x8*>(
          Bfrag + ((size_t)((0 * 8 + t) * 4 + ks) * 64 + l) * 8);
      acc = __builtin_amdgcn_mfma_f32_16x16x32_bf16(a[ks], *bp, acc, 0, 0, 0);
    }
    #pragma unroll
    for (int j = 0; j < 4; ++j) {
      int r = r0 + j;
      if (r < n) xlb[(size_t)r * 128 + t * 16 + cb] = f2bf_rne(acc[j]);
    }
  }
  #pragma unroll
  for (int t = 0; t < 8; ++t) {
    f32x4 acc = {0.f, 0.f, 0.f, 0.f};
    #pragma unroll
    for (int ks = 0; ks < 4; ++ks) {
      const bf16x8* bp = reinterpret_cast<const bf16x8*>(
          Bfrag + ((size_t)((1 * 8 + t) * 4 + ks) * 64 + l) * 8);
      acc = __builtin_amdgcn_mfma_f32_16x16x32_bf16(a[ks], *bp, acc, 0, 0, 0);
    }
    #pragma unroll
    for (int j = 0; j < 4; ++j) {
      int r = r0 + j;
      if (r < n) xr[(size_t)r * 128 + t * 16 + cb] = acc[j];
    }
  }
}

// ---------------- bucket scatter: edges -> 16-dst buckets (packed words) ----------
// word = bucket(12) | ldst(4) | src(16); fixed SLOT capacity per bucket.
__global__ __launch_bounds__(256) void bucket_scatter(
    const int* __restrict__ ei, int* __restrict__ gcur,
    int* __restrict__ ebuf, int E, int E2, int nbk) {
  __shared__ int hist[HWORDS];
  const int t = threadIdx.x;
  for (int i = t; i < HWORDS; i += 256) hist[i] = 0;
  __syncthreads();
  unsigned wcache[NPT];
  const int base = blockIdx.x * (256 * NPT);
  #pragma unroll
  for (int i = 0; i < NPT; ++i) {
    int e = base + i * 256 + t;
    unsigned w = 0xFFFFFFFFu;
    if (e < E2) {
      int src, dst;
      if (e < E) { src = ei[e]; dst = ei[E + e]; }
      else       { src = e - E; dst = e - E; }
      w = ((unsigned)(dst >> BSH) << 20) | ((unsigned)(dst & (BDST - 1)) << 16)
          | (unsigned)src;
      atomicAdd(&hist[dst >> BSH], 1);
    }
    wcache[i] = w;
  }
  __syncthreads();
  for (int b = t; b < nbk; b += 256) {
    int c = hist[b];
    if (c) hist[b] = atomicAdd(&gcur[b], c);   // hist[b] := global base
  }
  __syncthreads();
  #pragma unroll
  for (int i = 0; i < NPT; ++i) {
    unsigned w = wcache[i];
    if (w == 0xFFFFFFFFu) continue;
    int b = w >> 20;
    int pos = atomicAdd(&hist[b], 1);
    if (pos < SLOT) ebuf[b * SLOT + pos] = (int)(w & 0xFFFFF);
  }
}

// ---------------- fused per-bucket: local CSR in LDS + softmax-aggregate ----------
// block = bucket of 16 dsts; 4 waves x 4 dsts. Lane q=lane&31 owns channels
// 4q..4q+3 (head q>>3); halves (hf=lane>>5) process alternating edges.
__global__ __launch_bounds__(256) void fused_aggr(
    const int* __restrict__ gcur, const int* __restrict__ ebuf,
    const unsigned char* __restrict__ xb,   // xlb as bytes ([n] rows of 256B)
    const float* __restrict__ xr, const float* __restrict__ att,
    float* __restrict__ out, int n) {
  __shared__ int eraw[SLOT];
  __shared__ int elist[SLOT + 16];
  __shared__ int ldeg[BDST];
  __shared__ int lrow[BDST + 1];
  __shared__ int lcur[BDST];
  const int b = blockIdx.x;
  const int t = threadIdx.x;
  const int cnt = min(gcur[b], SLOT);
  if (t < BDST) ldeg[t] = 0;
  __syncthreads();
  for (int i = t; i < cnt; i += 256) {
    int w = ebuf[b * SLOT + i];
    eraw[i] = w;
    atomicAdd(&ldeg[(w >> 16) & (BDST - 1)], 1);
  }
  __syncthreads();
  if (t < BDST) {                       // 16-lane exclusive scan (wave 0)
    int v = ldeg[t];
    int incl = v;
    #pragma unroll
    for (int d = 1; d < BDST; d <<= 1) {
      int u = __shfl_up(incl, d);
      if (t >= d) incl += u;
    }
    lrow[t] = incl - v;
    lcur[t] = incl - v;
    if (t == BDST - 1) lrow[BDST] = incl;
  }
  __syncthreads();
  for (int i = t; i < cnt; i += 256) {
    int w = eraw[i];
    int pos = atomicAdd(&lcur[(w >> 16) & (BDST - 1)], 1);
    elist[pos] = (w & 0xFFFF) << 8;     // src byte-offset into xlb
  }
  if (t < 16) elist[cnt + t] = 0;       // pad: safe row-0 offsets for over-reads
  __syncthreads();

  const int wv = t >> 6, lane = t & 63;
  const int q = lane & 31, hf = lane >> 5;
  const float4 at4 = *reinterpret_cast<const float4*>(att + q * 4);

  #define LDE(st) (*reinterpret_cast<const uint2*>( \
      xb + (size_t)(unsigned)ep[2 * (st) + hf] + q * 8))
  #define STEP(V, ebase) { \
    float x0 = __uint_as_float((V).x << 16); \
    float x1 = __uint_as_float((V).x & 0xffff0000u); \
    float x2 = __uint_as_float((V).y << 16); \
    float x3 = __uint_as_float((V).y & 0xffff0000u); \
    float t0 = x0 + xr4.x; t0 = fmaxf(t0, NEG_SLOPE * t0); \
    float t1 = x1 + xr4.y; t1 = fmaxf(t1, NEG_SLOPE * t1); \
    float t2 = x2 + xr4.z; t2 = fmaxf(t2, NEG_SLOPE * t2); \
    float t3 = x3 + xr4.w; t3 = fmaxf(t3, NEG_SLOPE * t3); \
    float p = fmaf(t3, at4.w, fmaf(t2, at4.z, fmaf(t1, at4.y, t0 * at4.x))); \
    p += __shfl_xor(p, 1); \
    p += __shfl_xor(p, 2); \
    p += __shfl_xor(p, 4); \
    float w = ((ebase) + hf < deg) ? __expf(p) : 0.f; \
    s += w; \
    a0 = fmaf(w, x0, a0); a1 = fmaf(w, x1, a1); \
    a2 = fmaf(w, x2, a2); a3 = fmaf(w, x3, a3); }

  for (int j = 0; j < 4; ++j) {
    const int ldst = wv * 4 + j;
    const int node = b * BDST + ldst;
    if (node >= n) break;
    const float4 xr4 = *reinterpret_cast<const float4*>(xr + (size_t)node * 128 + q * 4);
    const int k0 = lrow[ldst];
    const int deg = lrow[ldst + 1] - k0;   // >= 1 (self-loop)
    const int* ep = elist + k0;

    uint2 V0 = LDE(0), V1 = LDE(1), V2 = LDE(2), V3 = LDE(3);
    float s = 0.f, a0 = 0.f, a1 = 0.f, a2 = 0.f, a3 = 0.f;
    const int S = (deg + 1) >> 1;         // steps (2 edges each)
    for (int i = 0; i < S; i += 2) {
      STEP(V0, 2 * i)
      STEP(V1, 2 * i + 2)
      V0 = V2; V1 = V3;
      if (2 * i + 8 < deg)  V2 = LDE(i + 4);
      if (2 * i + 10 < deg) V3 = LDE(i + 5);
    }
    // combine halves
    s  += __shfl_xor(s, 32);
    a0 += __shfl_xor(a0, 32);
    a1 += __shfl_xor(a1, 32);
    a2 += __shfl_xor(a2, 32);
    a3 += __shfl_xor(a3, 32);
    float inv = 1.f / (s + 1e-16f);
    if (hf == 0)
      *reinterpret_cast<float4*>(out + (size_t)node * 128 + q * 4) =
          make_float4(a0 * inv, a1 * inv, a2 * inv, a3 * inv);
  }
  #undef STEP
  #undef LDE
}

// ---------------- GraphNorm stats: sorted-batch chunked flush ----------------
__global__ __launch_bounds__(128) void gn_stats(
    const float* __restrict__ out, const float* __restrict__ bias,
    const int* __restrict__ batch, float* __restrict__ gsum,
    float* __restrict__ gsumsq, int* __restrict__ gcnt, int n) {
  const int c = threadIdx.x;
  const int n0 = blockIdx.x * CHUNK;
  const int n1 = min(n0 + CHUNK, n);
  const float bc = bias[c];
  float bsum = 0.f, bsq = 0.f;
  int cnt = 0;
  int curg = batch[n0];
  for (int nid = n0; nid < n1; ++nid) {
    int g = batch[nid];                    // uniform across block -> broadcast
    if (g != curg) {
      atomicAdd(&gsum[curg * 128 + c], bsum);
      atomicAdd(&gsumsq[curg * 128 + c], bsq);
      if (c == 0) atomicAdd(&gcnt[curg], cnt);
      bsum = 0.f; bsq = 0.f; cnt = 0; curg = g;
    }
    float v = out[(size_t)nid * 128 + c] + bc;
    bsum += v; bsq += v * v; ++cnt;
  }
  atomicAdd(&gsum[curg * 128 + c], bsum);
  atomicAdd(&gsumsq[curg * 128 + c], bsq);
  if (c == 0) atomicAdd(&gcnt[curg], cnt);
}

// ---------------- fold GraphNorm into per-(g,c) scale K and shift S ----------------
__global__ __launch_bounds__(128) void gn_prep(
    const float* __restrict__ gsum, const float* __restrict__ gsumsq,
    const int* __restrict__ gcnt, const float* __restrict__ bias,
    const float* __restrict__ msc, const float* __restrict__ w,
    const float* __restrict__ b, float* __restrict__ K, float* __restrict__ S) {
  int g = blockIdx.x, c = threadIdx.x;
  float cnt = (float)max(gcnt[g], 1);
  float mean = gsum[g * 128 + c] / cnt;
  float a = msc[c];
  float var = gsumsq[g * 128 + c] / cnt - mean * mean * (2.f * a - a * a);
  float k = rsqrtf(var + GN_EPS) * w[c];
  K[g * 128 + c] = k;
  S[g * 128 + c] = (bias[c] - mean * a) * k + b[c];
}

// ---------------- normalize + ELU (in place on out) ----------------
__global__ __launch_bounds__(256) void gn_norm(
    float* __restrict__ out, const int* __restrict__ batch,
    const float* __restrict__ K, const float* __restrict__ S, int n) {
  long long i = (long long)blockIdx.x * 256 + threadIdx.x;
  if (i >= (long long)n * 128) return;
  int nid = (int)(i >> 7), c = (int)(i & 127);
  int g = batch[nid];
  float val = fmaf(out[i], K[g * 128 + c], S[g * 128 + c]);
  out[i] = (val > 0.f) ? val : (__expf(val) - 1.f);
}

extern "C" void kernel_launch(void* const* d_in, const int* in_sizes, int n_in,
                              void* d_out, int out_size, void* d_ws, size_t ws_size,
                              hipStream_t stream) {
  const float* x    = (const float*)d_in[0];
  const int*   ei   = (const int*)d_in[1];
  const int*   batch= (const int*)d_in[2];
  const float* Wl   = (const float*)d_in[3];
  const float* Wr   = (const float*)d_in[4];
  const float* att  = (const float*)d_in[5];
  const float* bias = (const float*)d_in[6];
  const float* gw   = (const float*)d_in[7];
  const float* gb   = (const float*)d_in[8];
  const float* gms  = (const float*)d_in[9];
  float* out = (float*)d_out;

  const int n  = in_sizes[0] / 128;
  const int E  = in_sizes[1] / 2;
  const int E2 = E + n;
  const int NBK = (n + BDST - 1) / BDST;

  // workspace layout (zero-init region first: gcur|gcnt|gsum|gsumsq)
  char* ws = (char*)d_ws;
  size_t off = 0;
  int*   gcur    = (int*)(ws + off); off += (size_t)((NBK + 63) & ~63) * 4;
  int*   gcnt    = (int*)(ws + off); off += GG * 4;
  float* gsum    = (float*)(ws + off); off += GG * 128 * 4;
  float* gsumsq  = (float*)(ws + off); off += GG * 128 * 4;
  size_t zero_bytes = off;
  int*   ebuf    = (int*)(ws + off); off += (size_t)NBK * SLOT * 4;
  unsigned short* xlb = (unsigned short*)(ws + off); off += (size_t)n * 128 * 2;
  float* xr      = (float*)(ws + off); off += (size_t)n * 128 * 4;
  unsigned short* Bfrag = (unsigned short*)(ws + off); off += 64 * 64 * 8 * 2;
  float* gK      = (float*)(ws + off); off += GG * 128 * 4;
  float* gS      = (float*)(ws + off); off += GG * 128 * 4;

  hipMemsetAsync(ws, 0, zero_bytes, stream);

  bucket_scatter<<<(E2 + 256 * NPT - 1) / (256 * NPT), 256, 0, stream>>>(
      ei, gcur, ebuf, E, E2, NBK);

  wpack<<<16, 256, 0, stream>>>(Wl, Wr, (unsigned short*)Bfrag);
  {
    int waves = (n + 15) / 16;
    int blocks = (waves * 64 + 255) / 256;
    gemm_mfma<<<blocks, 256, 0, stream>>>(x, Bfrag, xlb, xr, n);
  }

  fused_aggr<<<NBK, 256, 0, stream>>>(gcur, ebuf, (const unsigned char*)xlb,
                                      xr, att, out, n);

  gn_stats<<<(n + CHUNK - 1) / CHUNK, 128, 0, stream>>>(out, bias, batch, gsum, gsumsq, gcnt, n);
  gn_prep<<<GG, 128, 0, stream>>>(gsum, gsumsq, gcnt, bias, gms, gw, gb, gK, gS);

  long long t_nm = (long long)n * 128;
  gn_norm<<<(int)((t_nm + 255) / 256), 256, 0, stream>>>(out, batch, gK, gS, n);
}

// Round 13
// 116.894 us; speedup vs baseline: 1.8334x; 1.1192x over previous
//
#include <hip/hip_runtime.h>
#include <math.h>

#define HH 4
#define GG 64
#define CHUNK 64
#define BDST 16            // dsts per bucket
#define BSH  4             // log2(BDST)
#define SLOT 768           // max edges per bucket (mean ~272, +30 sigma)
#define NPT  16            // edges cached per thread in bucket_scatter
#define HWORDS 3328        // >= NBK, multiple of 256
constexpr float NEG_SLOPE = 0.2f;
constexpr float GN_EPS = 1e-5f;

typedef __attribute__((ext_vector_type(8))) short bf16x8;
typedef __attribute__((ext_vector_type(4))) float f32x4;

__device__ __forceinline__ unsigned short f2bf_rne(float f) {
  unsigned u = __float_as_uint(f);
  u += 0x7fffu + ((u >> 16) & 1u);       // round-to-nearest-even
  return (unsigned short)(u >> 16);
}

// ---------------- pack Wl|Wr into MFMA B-fragment layout (bf16) ----------------
__global__ __launch_bounds__(256) void wpack(
    const float* __restrict__ Wl, const float* __restrict__ Wr,
    unsigned short* __restrict__ Bfrag) {
  int tid = blockIdx.x * 256 + threadIdx.x;       // 0 .. 64*64-1
  int f = tid >> 6, l = tid & 63;
  int m = f >> 5;                                  // 0=Wl 1=Wr
  int t = (f >> 2) & 7;                            // col-tile 0..7
  int ks = f & 3;                                  // k-subtile 0..3
  int col = t * 16 + (l & 15);
  int k0 = ks * 32 + (l >> 4) * 8;
  const float* W = m ? Wr : Wl;
  unsigned short* dst = Bfrag + ((size_t)f * 64 + l) * 8;
  #pragma unroll
  for (int j = 0; j < 8; ++j)
    dst[j] = f2bf_rne(W[(k0 + j) * 128 + col]);
}

// ---------------- merged prep: blocks [0,SB) bucket-scatter, [SB,..) MFMA GEMM ----
// scatter: word = bucket(12) | ldst(4) | src(16); gemm: xlb=x@Wl(bf16), xr=x@Wr(f32)
__global__ __launch_bounds__(256) void prep_merged(
    const int* __restrict__ ei, int* __restrict__ gcur, int* __restrict__ ebuf,
    int E, int E2, int nbk, int SB,
    const float* __restrict__ x, const unsigned short* __restrict__ Bfrag,
    unsigned short* __restrict__ xlb, float* __restrict__ xr, int n) {
  __shared__ int hist[HWORDS];
  const int t = threadIdx.x;
  if ((int)blockIdx.x < SB) {
    // ---------- bucket scatter ----------
    for (int i = t; i < HWORDS; i += 256) hist[i] = 0;
    __syncthreads();
    unsigned wcache[NPT];
    const int base = blockIdx.x * (256 * NPT);
    #pragma unroll
    for (int i = 0; i < NPT; ++i) {
      int e = base + i * 256 + t;
      unsigned w = 0xFFFFFFFFu;
      if (e < E2) {
        int src, dst;
        if (e < E) { src = ei[e]; dst = ei[E + e]; }
        else       { src = e - E; dst = e - E; }
        w = ((unsigned)(dst >> BSH) << 20) | ((unsigned)(dst & (BDST - 1)) << 16)
            | (unsigned)src;
        atomicAdd(&hist[dst >> BSH], 1);
      }
      wcache[i] = w;
    }
    __syncthreads();
    for (int b = t; b < nbk; b += 256) {
      int c = hist[b];
      if (c) hist[b] = atomicAdd(&gcur[b], c);   // hist[b] := global base
    }
    __syncthreads();
    #pragma unroll
    for (int i = 0; i < NPT; ++i) {
      unsigned w = wcache[i];
      if (w == 0xFFFFFFFFu) continue;
      int b = w >> 20;
      int pos = atomicAdd(&hist[b], 1);
      if (pos < SLOT) ebuf[b * SLOT + pos] = (int)(w & 0xFFFFF);
    }
    return;
  }
  // ---------- MFMA GEMM ----------
  const int wave = ((blockIdx.x - SB) * 256 + t) >> 6;
  if (wave * 16 >= n) return;
  const int l = t & 63;
  const int arow = min(wave * 16 + (l & 15), n - 1);
  const float4* xrow = reinterpret_cast<const float4*>(x + (size_t)arow * 128);

  bf16x8 a[4];
  #pragma unroll
  for (int ks = 0; ks < 4; ++ks) {
    float4 lo = xrow[ks * 8 + (l >> 4) * 2];
    float4 hi = xrow[ks * 8 + (l >> 4) * 2 + 1];
    bf16x8 v;
    v[0] = (short)f2bf_rne(lo.x); v[1] = (short)f2bf_rne(lo.y);
    v[2] = (short)f2bf_rne(lo.z); v[3] = (short)f2bf_rne(lo.w);
    v[4] = (short)f2bf_rne(hi.x); v[5] = (short)f2bf_rne(hi.y);
    v[6] = (short)f2bf_rne(hi.z); v[7] = (short)f2bf_rne(hi.w);
    a[ks] = v;
  }

  const int r0 = wave * 16 + (l >> 4) * 4;        // C/D rows for this lane
  const int cb = l & 15;                          // C/D col within tile
  #pragma unroll
  for (int tt = 0; tt < 8; ++tt) {
    f32x4 acc = {0.f, 0.f, 0.f, 0.f};
    #pragma unroll
    for (int ks = 0; ks < 4; ++ks) {
      const bf16x8* bp = reinterpret_cast<const bf16x8*>(
          Bfrag + ((size_t)((0 * 8 + tt) * 4 + ks) * 64 + l) * 8);
      acc = __builtin_amdgcn_mfma_f32_16x16x32_bf16(a[ks], *bp, acc, 0, 0, 0);
    }
    #pragma unroll
    for (int j = 0; j < 4; ++j) {
      int r = r0 + j;
      if (r < n) xlb[(size_t)r * 128 + tt * 16 + cb] = f2bf_rne(acc[j]);
    }
  }
  #pragma unroll
  for (int tt = 0; tt < 8; ++tt) {
    f32x4 acc = {0.f, 0.f, 0.f, 0.f};
    #pragma unroll
    for (int ks = 0; ks < 4; ++ks) {
      const bf16x8* bp = reinterpret_cast<const bf16x8*>(
          Bfrag + ((size_t)((1 * 8 + tt) * 4 + ks) * 64 + l) * 8);
      acc = __builtin_amdgcn_mfma_f32_16x16x32_bf16(a[ks], *bp, acc, 0, 0, 0);
    }
    #pragma unroll
    for (int j = 0; j < 4; ++j) {
      int r = r0 + j;
      if (r < n) xr[(size_t)r * 128 + tt * 16 + cb] = acc[j];
    }
  }
}

// ---------------- fused per-bucket: local CSR in LDS + softmax-aggregate ----------
// block = bucket of 16 dsts; 4 waves x 4 dsts. 16-lane groups gi=lane>>4 process
// alternating edges; within group, lane u=lane&15 owns channels 8u..8u+7 (head u>>2).
__global__ __launch_bounds__(256) void fused_aggr(
    const int* __restrict__ gcur, const int* __restrict__ ebuf,
    const unsigned char* __restrict__ xb,   // xlb as bytes ([n] rows of 256B)
    const float* __restrict__ xr, const float* __restrict__ att,
    float* __restrict__ out, int n) {
  __shared__ int eraw[SLOT];
  __shared__ int elist[SLOT + 16];
  __shared__ int ldeg[BDST];
  __shared__ int lrow[BDST + 1];
  __shared__ int lcur[BDST];
  const int b = blockIdx.x;
  const int t = threadIdx.x;
  const int cnt = min(gcur[b], SLOT);
  if (t < BDST) ldeg[t] = 0;
  __syncthreads();
  for (int i = t; i < cnt; i += 256) {
    int w = ebuf[b * SLOT + i];
    eraw[i] = w;
    atomicAdd(&ldeg[(w >> 16) & (BDST - 1)], 1);
  }
  __syncthreads();
  if (t < BDST) {                       // 16-lane exclusive scan (wave 0)
    int v = ldeg[t];
    int incl = v;
    #pragma unroll
    for (int d = 1; d < BDST; d <<= 1) {
      int u = __shfl_up(incl, d);
      if (t >= d) incl += u;
    }
    lrow[t] = incl - v;
    lcur[t] = incl - v;
    if (t == BDST - 1) lrow[BDST] = incl;
  }
  __syncthreads();
  for (int i = t; i < cnt; i += 256) {
    int w = eraw[i];
    int pos = atomicAdd(&lcur[(w >> 16) & (BDST - 1)], 1);
    elist[pos] = (w & 0xFFFF) << 8;     // src byte-offset into xlb
  }
  if (t < 16) elist[cnt + t] = 0;       // pad: safe row-0 offsets for over-reads
  __syncthreads();

  const int wv = t >> 6, lane = t & 63;
  const int u = lane & 15, gi = lane >> 4;
  const float4 atA = *reinterpret_cast<const float4*>(att + u * 8);
  const float4 atB = *reinterpret_cast<const float4*>(att + u * 8 + 4);

  #define LDE(st) (*reinterpret_cast<const uint4*>( \
      xb + (size_t)(unsigned)ep[4 * (st) + gi] + u * 16))
  #define STEP(V, ebase) { \
    float x0 = __uint_as_float((V).x << 16); \
    float x1 = __uint_as_float((V).x & 0xffff0000u); \
    float x2 = __uint_as_float((V).y << 16); \
    float x3 = __uint_as_float((V).y & 0xffff0000u); \
    float x4 = __uint_as_float((V).z << 16); \
    float x5 = __uint_as_float((V).z & 0xffff0000u); \
    float x6 = __uint_as_float((V).w << 16); \
    float x7 = __uint_as_float((V).w & 0xffff0000u); \
    float t0 = x0 + xrA.x; t0 = fmaxf(t0, NEG_SLOPE * t0); \
    float t1 = x1 + xrA.y; t1 = fmaxf(t1, NEG_SLOPE * t1); \
    float t2 = x2 + xrA.z; t2 = fmaxf(t2, NEG_SLOPE * t2); \
    float t3 = x3 + xrA.w; t3 = fmaxf(t3, NEG_SLOPE * t3); \
    float t4 = x4 + xrB.x; t4 = fmaxf(t4, NEG_SLOPE * t4); \
    float t5 = x5 + xrB.y; t5 = fmaxf(t5, NEG_SLOPE * t5); \
    float t6 = x6 + xrB.z; t6 = fmaxf(t6, NEG_SLOPE * t6); \
    float t7 = x7 + xrB.w; t7 = fmaxf(t7, NEG_SLOPE * t7); \
    float p = t0 * atA.x; \
    p = fmaf(t1, atA.y, p); p = fmaf(t2, atA.z, p); p = fmaf(t3, atA.w, p); \
    p = fmaf(t4, atB.x, p); p = fmaf(t5, atB.y, p); p = fmaf(t6, atB.z, p); \
    p = fmaf(t7, atB.w, p); \
    p += __shfl_xor(p, 1); \
    p += __shfl_xor(p, 2); \
    float w = ((ebase) + gi < deg) ? __expf(p) : 0.f; \
    s += w; \
    a0 = fmaf(w, x0, a0); a1 = fmaf(w, x1, a1); \
    a2 = fmaf(w, x2, a2); a3 = fmaf(w, x3, a3); \
    a4 = fmaf(w, x4, a4); a5 = fmaf(w, x5, a5); \
    a6 = fmaf(w, x6, a6); a7 = fmaf(w, x7, a7); }

  for (int j = 0; j < 4; ++j) {
    const int ldst = wv * 4 + j;
    const int node = b * BDST + ldst;
    if (node >= n) break;
    const float4 xrA = *reinterpret_cast<const float4*>(xr + (size_t)node * 128 + u * 8);
    const float4 xrB = *reinterpret_cast<const float4*>(xr + (size_t)node * 128 + u * 8 + 4);
    const int k0 = lrow[ldst];
    const int deg = lrow[ldst + 1] - k0;   // >= 1 (self-loop)
    const int* ep = elist + k0;

    uint4 V0 = LDE(0), V1 = LDE(1), V2 = LDE(2);
    float s = 0.f;
    float a0 = 0.f, a1 = 0.f, a2 = 0.f, a3 = 0.f;
    float a4 = 0.f, a5 = 0.f, a6 = 0.f, a7 = 0.f;
    const int S = (deg + 3) >> 2;         // steps (4 edges each)
    for (int i = 0; i < S; ++i) {
      uint4 C = V0; V0 = V1; V1 = V2;
      if (4 * i + 12 < deg) V2 = LDE(i + 3);   // step i+3 exists <=> 4i+12 < deg
      STEP(C, 4 * i)
    }
    // combine the 4 groups
    s  += __shfl_xor(s, 16);  s  += __shfl_xor(s, 32);
    a0 += __shfl_xor(a0, 16); a0 += __shfl_xor(a0, 32);
    a1 += __shfl_xor(a1, 16); a1 += __shfl_xor(a1, 32);
    a2 += __shfl_xor(a2, 16); a2 += __shfl_xor(a2, 32);
    a3 += __shfl_xor(a3, 16); a3 += __shfl_xor(a3, 32);
    a4 += __shfl_xor(a4, 16); a4 += __shfl_xor(a4, 32);
    a5 += __shfl_xor(a5, 16); a5 += __shfl_xor(a5, 32);
    a6 += __shfl_xor(a6, 16); a6 += __shfl_xor(a6, 32);
    a7 += __shfl_xor(a7, 16); a7 += __shfl_xor(a7, 32);
    float inv = 1.f / (s + 1e-16f);
    if (gi == 0) {
      float* op = out + (size_t)node * 128 + u * 8;
      *reinterpret_cast<float4*>(op) =
          make_float4(a0 * inv, a1 * inv, a2 * inv, a3 * inv);
      *reinterpret_cast<float4*>(op + 4) =
          make_float4(a4 * inv, a5 * inv, a6 * inv, a7 * inv);
    }
  }
  #undef STEP
  #undef LDE
}

// ---------------- GraphNorm stats: sorted-batch chunked flush ----------------
__global__ __launch_bounds__(128) void gn_stats(
    const float* __restrict__ out, const float* __restrict__ bias,
    const int* __restrict__ batch, float* __restrict__ gsum,
    float* __restrict__ gsumsq, int* __restrict__ gcnt, int n) {
  const int c = threadIdx.x;
  const int n0 = blockIdx.x * CHUNK;
  const int n1 = min(n0 + CHUNK, n);
  const float bc = bias[c];
  float bsum = 0.f, bsq = 0.f;
  int cnt = 0;
  int curg = batch[n0];
  for (int nid = n0; nid < n1; ++nid) {
    int g = batch[nid];                    // uniform across block -> broadcast
    if (g != curg) {
      atomicAdd(&gsum[curg * 128 + c], bsum);
      atomicAdd(&gsumsq[curg * 128 + c], bsq);
      if (c == 0) atomicAdd(&gcnt[curg], cnt);
      bsum = 0.f; bsq = 0.f; cnt = 0; curg = g;
    }
    float v = out[(size_t)nid * 128 + c] + bc;
    bsum += v; bsq += v * v; ++cnt;
  }
  atomicAdd(&gsum[curg * 128 + c], bsum);
  atomicAdd(&gsumsq[curg * 128 + c], bsq);
  if (c == 0) atomicAdd(&gcnt[curg], cnt);
}

// ---------------- fold GraphNorm into per-(g,c) scale K and shift S ----------------
__global__ __launch_bounds__(128) void gn_prep(
    const float* __restrict__ gsum, const float* __restrict__ gsumsq,
    const int* __restrict__ gcnt, const float* __restrict__ bias,
    const float* __restrict__ msc, const float* __restrict__ w,
    const float* __restrict__ b, float* __restrict__ K, float* __restrict__ S) {
  int g = blockIdx.x, c = threadIdx.x;
  float cnt = (float)max(gcnt[g], 1);
  float mean = gsum[g * 128 + c] / cnt;
  float a = msc[c];
  float var = gsumsq[g * 128 + c] / cnt - mean * mean * (2.f * a - a * a);
  float k = rsqrtf(var + GN_EPS) * w[c];
  K[g * 128 + c] = k;
  S[g * 128 + c] = (bias[c] - mean * a) * k + b[c];
}

// ---------------- normalize + ELU (in place on out), float4 ----------------
__global__ __launch_bounds__(256) void gn_norm(
    float* __restrict__ out, const int* __restrict__ batch,
    const float* __restrict__ K, const float* __restrict__ S, int n) {
  int i = blockIdx.x * 256 + threadIdx.x;     // one thread per 4 channels
  if (i >= n * 32) return;
  int nid = i >> 5, c4 = (i & 31) * 4;
  int g = batch[nid];
  const float4 k4 = *reinterpret_cast<const float4*>(K + g * 128 + c4);
  const float4 s4 = *reinterpret_cast<const float4*>(S + g * 128 + c4);
  float* op = out + (size_t)nid * 128 + c4;
  float4 v = *reinterpret_cast<const float4*>(op);
  v.x = fmaf(v.x, k4.x, s4.x); v.x = (v.x > 0.f) ? v.x : (__expf(v.x) - 1.f);
  v.y = fmaf(v.y, k4.y, s4.y); v.y = (v.y > 0.f) ? v.y : (__expf(v.y) - 1.f);
  v.z = fmaf(v.z, k4.z, s4.z); v.z = (v.z > 0.f) ? v.z : (__expf(v.z) - 1.f);
  v.w = fmaf(v.w, k4.w, s4.w); v.w = (v.w > 0.f) ? v.w : (__expf(v.w) - 1.f);
  *reinterpret_cast<float4*>(op) = v;
}

extern "C" void kernel_launch(void* const* d_in, const int* in_sizes, int n_in,
                              void* d_out, int out_size, void* d_ws, size_t ws_size,
                              hipStream_t stream) {
  const float* x    = (const float*)d_in[0];
  const int*   ei   = (const int*)d_in[1];
  const int*   batch= (const int*)d_in[2];
  const float* Wl   = (const float*)d_in[3];
  const float* Wr   = (const float*)d_in[4];
  const float* att  = (const float*)d_in[5];
  const float* bias = (const float*)d_in[6];
  const float* gw   = (const float*)d_in[7];
  const float* gb   = (const float*)d_in[8];
  const float* gms  = (const float*)d_in[9];
  float* out = (float*)d_out;

  const int n  = in_sizes[0] / 128;
  const int E  = in_sizes[1] / 2;
  const int E2 = E + n;
  const int NBK = (n + BDST - 1) / BDST;
  const int SB = (E2 + 256 * NPT - 1) / (256 * NPT);
  const int GB = (((n + 15) / 16) * 64 + 255) / 256;

  // workspace layout (zero-init region first: gcur|gcnt|gsum|gsumsq)
  char* ws = (char*)d_ws;
  size_t off = 0;
  int*   gcur    = (int*)(ws + off); off += (size_t)((NBK + 63) & ~63) * 4;
  int*   gcnt    = (int*)(ws + off); off += GG * 4;
  float* gsum    = (float*)(ws + off); off += GG * 128 * 4;
  float* gsumsq  = (float*)(ws + off); off += GG * 128 * 4;
  size_t zero_bytes = off;
  int*   ebuf    = (int*)(ws + off); off += (size_t)NBK * SLOT * 4;
  unsigned short* xlb = (unsigned short*)(ws + off); off += (size_t)n * 128 * 2;
  float* xr      = (float*)(ws + off); off += (size_t)n * 128 * 4;
  unsigned short* Bfrag = (unsigned short*)(ws + off); off += 64 * 64 * 8 * 2;
  float* gK      = (float*)(ws + off); off += GG * 128 * 4;
  float* gS      = (float*)(ws + off); off += GG * 128 * 4;

  hipMemsetAsync(ws, 0, zero_bytes, stream);

  wpack<<<16, 256, 0, stream>>>(Wl, Wr, (unsigned short*)Bfrag);

  prep_merged<<<SB + GB, 256, 0, stream>>>(ei, gcur, ebuf, E, E2, NBK, SB,
                                           x, Bfrag, xlb, xr, n);

  fused_aggr<<<NBK, 256, 0, stream>>>(gcur, ebuf, (const unsigned char*)xlb,
                                      xr, att, out, n);

  gn_stats<<<(n + CHUNK - 1) / CHUNK, 128, 0, stream>>>(out, bias, batch, gsum, gsumsq, gcnt, n);
  gn_prep<<<GG, 128, 0, stream>>>(gsum, gsumsq, gcnt, bias, gms, gw, gb, gK, gS);

  gn_norm<<<(n * 32 + 255) / 256, 256, 0, stream>>>(out, batch, gK, gS, n);
}

// Round 15
// 116.068 us; speedup vs baseline: 1.8464x; 1.0071x over previous
//
#include <hip/hip_runtime.h>
#include <math.h>

#define HH 4
#define GG 64
#define CHUNK 64
#define BDST 16            // dsts per bucket
#define BSH  4             // log2(BDST)
#define SLOT 768           // max edges per bucket (mean ~272, +30 sigma)
#define NPT  16            // edges cached per thread in bucket_scatter
#define HWORDS 3328        // >= NBK, multiple of 256
constexpr float NEG_SLOPE = 0.2f;
constexpr float GN_EPS = 1e-5f;

typedef __attribute__((ext_vector_type(8))) short bf16x8;
typedef __attribute__((ext_vector_type(4))) float f32x4;

__device__ __forceinline__ unsigned short f2bf_rne(float f) {
  unsigned u = __float_as_uint(f);
  u += 0x7fffu + ((u >> 16) & 1u);       // round-to-nearest-even
  return (unsigned short)(u >> 16);
}

// ---------------- pack Wl|Wr into MFMA B-fragment layout (bf16) ----------------
__global__ __launch_bounds__(256) void wpack(
    const float* __restrict__ Wl, const float* __restrict__ Wr,
    unsigned short* __restrict__ Bfrag) {
  int tid = blockIdx.x * 256 + threadIdx.x;       // 0 .. 64*64-1
  int f = tid >> 6, l = tid & 63;
  int m = f >> 5;                                  // 0=Wl 1=Wr
  int t = (f >> 2) & 7;                            // col-tile 0..7
  int ks = f & 3;                                  // k-subtile 0..3
  int col = t * 16 + (l & 15);
  int k0 = ks * 32 + (l >> 4) * 8;
  const float* W = m ? Wr : Wl;
  unsigned short* dst = Bfrag + ((size_t)f * 64 + l) * 8;
  #pragma unroll
  for (int j = 0; j < 8; ++j)
    dst[j] = f2bf_rne(W[(k0 + j) * 128 + col]);
}

// ---------------- merged prep: blocks [0,SB) bucket-scatter, [SB,..) MFMA GEMM ----
// gemm also emits PER-HEAD dots dA[n][4] = att_h.xl_h, dB[n][4] = att_h.xr_h.
__global__ __launch_bounds__(256) void prep_merged(
    const int* __restrict__ ei, int* __restrict__ gcur, int* __restrict__ ebuf,
    int E, int E2, int nbk, int SB,
    const float* __restrict__ x, const unsigned short* __restrict__ Bfrag,
    const float* __restrict__ att,
    unsigned short* __restrict__ xlb, unsigned short* __restrict__ xrb,
    float* __restrict__ dA, float* __restrict__ dB, int n) {
  __shared__ int hist[HWORDS];
  const int t = threadIdx.x;
  if ((int)blockIdx.x < SB) {
    // ---------- bucket scatter ----------
    for (int i = t; i < HWORDS; i += 256) hist[i] = 0;
    __syncthreads();
    unsigned wcache[NPT];
    const int base = blockIdx.x * (256 * NPT);
    #pragma unroll
    for (int i = 0; i < NPT; ++i) {
      int e = base + i * 256 + t;
      unsigned w = 0xFFFFFFFFu;
      if (e < E2) {
        int src, dst;
        if (e < E) { src = ei[e]; dst = ei[E + e]; }
        else       { src = e - E; dst = e - E; }
        w = ((unsigned)(dst >> BSH) << 20) | ((unsigned)(dst & (BDST - 1)) << 16)
            | (unsigned)src;
        atomicAdd(&hist[dst >> BSH], 1);
      }
      wcache[i] = w;
    }
    __syncthreads();
    for (int b = t; b < nbk; b += 256) {
      int c = hist[b];
      if (c) hist[b] = atomicAdd(&gcur[b], c);   // hist[b] := global base
    }
    __syncthreads();
    #pragma unroll
    for (int i = 0; i < NPT; ++i) {
      unsigned w = wcache[i];
      if (w == 0xFFFFFFFFu) continue;
      int b = w >> 20;
      int pos = atomicAdd(&hist[b], 1);
      if (pos < SLOT) ebuf[b * SLOT + pos] = (int)(w & 0xFFFFF);
    }
    return;
  }
  // ---------- MFMA GEMM ----------
  const int wave = ((blockIdx.x - SB) * 256 + t) >> 6;
  if (wave * 16 >= n) return;
  const int l = t & 63;
  const int arow = min(wave * 16 + (l & 15), n - 1);
  const float4* xrow = reinterpret_cast<const float4*>(x + (size_t)arow * 128);

  bf16x8 a[4];
  #pragma unroll
  for (int ks = 0; ks < 4; ++ks) {
    float4 lo = xrow[ks * 8 + (l >> 4) * 2];
    float4 hi = xrow[ks * 8 + (l >> 4) * 2 + 1];
    bf16x8 v;
    v[0] = (short)f2bf_rne(lo.x); v[1] = (short)f2bf_rne(lo.y);
    v[2] = (short)f2bf_rne(lo.z); v[3] = (short)f2bf_rne(lo.w);
    v[4] = (short)f2bf_rne(hi.x); v[5] = (short)f2bf_rne(hi.y);
    v[6] = (short)f2bf_rne(hi.z); v[7] = (short)f2bf_rne(hi.w);
    a[ks] = v;
  }

  const int r0 = wave * 16 + (l >> 4) * 4;        // C/D rows for this lane
  const int cb = l & 15;                          // C/D col within tile
  float pd[4] = {0.f, 0.f, 0.f, 0.f};
  #pragma unroll
  for (int tt = 0; tt < 8; ++tt) {                // head = tt>>1
    f32x4 acc = {0.f, 0.f, 0.f, 0.f};
    #pragma unroll
    for (int ks = 0; ks < 4; ++ks) {
      const bf16x8* bp = reinterpret_cast<const bf16x8*>(
          Bfrag + ((size_t)((0 * 8 + tt) * 4 + ks) * 64 + l) * 8);
      acc = __builtin_amdgcn_mfma_f32_16x16x32_bf16(a[ks], *bp, acc, 0, 0, 0);
    }
    float attv = att[tt * 16 + cb];
    #pragma unroll
    for (int j = 0; j < 4; ++j) {
      int r = r0 + j;
      unsigned short h = f2bf_rne(acc[j]);
      if (r < n) xlb[(size_t)r * 128 + tt * 16 + cb] = h;
      pd[j] = fmaf(__uint_as_float((unsigned)h << 16), attv, pd[j]);
    }
    if (tt & 1) {                                  // head tt>>1 complete
      #pragma unroll
      for (int j = 0; j < 4; ++j) {
        float v = pd[j];
        #pragma unroll
        for (int mk = 1; mk < 16; mk <<= 1) v += __shfl_xor(v, mk);
        if (cb == 0 && r0 + j < n) dA[(size_t)(r0 + j) * 4 + (tt >> 1)] = v;
        pd[j] = 0.f;
      }
    }
  }
  #pragma unroll
  for (int tt = 0; tt < 8; ++tt) {
    f32x4 acc = {0.f, 0.f, 0.f, 0.f};
    #pragma unroll
    for (int ks = 0; ks < 4; ++ks) {
      const bf16x8* bp = reinterpret_cast<const bf16x8*>(
          Bfrag + ((size_t)((1 * 8 + tt) * 4 + ks) * 64 + l) * 8);
      acc = __builtin_amdgcn_mfma_f32_16x16x32_bf16(a[ks], *bp, acc, 0, 0, 0);
    }
    float attv = att[tt * 16 + cb];
    #pragma unroll
    for (int j = 0; j < 4; ++j) {
      int r = r0 + j;
      unsigned short h = f2bf_rne(acc[j]);
      if (r < n) xrb[(size_t)r * 128 + tt * 16 + cb] = h;
      pd[j] = fmaf(__uint_as_float((unsigned)h << 16), attv, pd[j]);
    }
    if (tt & 1) {
      #pragma unroll
      for (int j = 0; j < 4; ++j) {
        float v = pd[j];
        #pragma unroll
        for (int mk = 1; mk < 16; mk <<= 1) v += __shfl_xor(v, mk);
        if (cb == 0 && r0 + j < n) dB[(size_t)(r0 + j) * 4 + (tt >> 1)] = v;
        pd[j] = 0.f;
      }
    }
  }
}

// ---------------- fused per-bucket: local CSR in LDS + softmax-aggregate ----------
// block = bucket of 16 dsts; 4 waves x 4 dsts. 16-lane groups gi=lane>>4 process
// alternating edges; lane u=lane&15 owns channels 8u..8u+7 (head u>>2).
// logit_h = 0.6*(dA_h[src]+dB_h[dst]) + 0.4*sum_h(att*|xl+xr|)
__global__ __launch_bounds__(256) void fused_aggr(
    const int* __restrict__ gcur, const int* __restrict__ ebuf,
    const unsigned char* __restrict__ xb,   // xlb bytes ([n] rows of 256B)
    const unsigned char* __restrict__ xrb,  // xrb bytes ([n] rows of 256B)
    const float* __restrict__ dA, const float* __restrict__ dB,
    const float* __restrict__ att, float* __restrict__ out, int n) {
  __shared__ int eraw[SLOT];
  __shared__ int elist[SLOT + 16];
  __shared__ int ldeg[BDST];
  __shared__ int lrow[BDST + 1];
  __shared__ int lcur[BDST];
  const int b = blockIdx.x;
  const int t = threadIdx.x;
  const int cnt = min(gcur[b], SLOT);
  if (t < BDST) ldeg[t] = 0;
  __syncthreads();
  for (int i = t; i < cnt; i += 256) {
    int w = ebuf[b * SLOT + i];
    eraw[i] = w;
    atomicAdd(&ldeg[(w >> 16) & (BDST - 1)], 1);
  }
  __syncthreads();
  if (t < BDST) {                       // 16-lane exclusive scan (wave 0)
    int v = ldeg[t];
    int incl = v;
    #pragma unroll
    for (int d = 1; d < BDST; d <<= 1) {
      int u = __shfl_up(incl, d);
      if (t >= d) incl += u;
    }
    lrow[t] = incl - v;
    lcur[t] = incl - v;
    if (t == BDST - 1) lrow[BDST] = incl;
  }
  __syncthreads();
  for (int i = t; i < cnt; i += 256) {
    int w = eraw[i];
    int pos = atomicAdd(&lcur[(w >> 16) & (BDST - 1)], 1);
    elist[pos] = (w & 0xFFFF) << 8;     // src byte-offset into xlb
  }
  if (t < 16) elist[cnt + t] = 0;       // pad: safe row-0 offsets for over-reads
  __syncthreads();

  const int wv = t >> 6, lane = t & 63;
  const int u = lane & 15, gi = lane >> 4;
  const int hh = u >> 2;                // head of this lane
  const float4 atA = *reinterpret_cast<const float4*>(att + u * 8);
  const float4 atB = *reinterpret_cast<const float4*>(att + u * 8 + 4);

  #define LDE(st) (*reinterpret_cast<const uint4*>( \
      xb + (size_t)(unsigned)ep[4 * (st) + gi] + u * 16))
  #define LDA(st) (dA[((unsigned)ep[4 * (st) + gi] >> 8) * 4 + hh])
  #define STEP(V, da, ebase) { \
    float x0 = __uint_as_float((V).x << 16); \
    float x1 = __uint_as_float((V).x & 0xffff0000u); \
    float x2 = __uint_as_float((V).y << 16); \
    float x3 = __uint_as_float((V).y & 0xffff0000u); \
    float x4 = __uint_as_float((V).z << 16); \
    float x5 = __uint_as_float((V).z & 0xffff0000u); \
    float x6 = __uint_as_float((V).w << 16); \
    float x7 = __uint_as_float((V).w & 0xffff0000u); \
    float p = fabsf(x0 + xr0) * atA.x; \
    p = fmaf(fabsf(x1 + xr1), atA.y, p); \
    p = fmaf(fabsf(x2 + xr2), atA.z, p); \
    p = fmaf(fabsf(x3 + xr3), atA.w, p); \
    p = fmaf(fabsf(x4 + xr4), atB.x, p); \
    p = fmaf(fabsf(x5 + xr5), atB.y, p); \
    p = fmaf(fabsf(x6 + xr6), atB.z, p); \
    p = fmaf(fabsf(x7 + xr7), atB.w, p); \
    p += __shfl_xor(p, 1); \
    p += __shfl_xor(p, 2); \
    float lg = fmaf(0.4f, p, fmaf(0.6f, (da), eB)); \
    float w = ((ebase) + gi < deg) ? __expf(lg) : 0.f; \
    s += w; \
    a0 = fmaf(w, x0, a0); a1 = fmaf(w, x1, a1); \
    a2 = fmaf(w, x2, a2); a3 = fmaf(w, x3, a3); \
    a4 = fmaf(w, x4, a4); a5 = fmaf(w, x5, a5); \
    a6 = fmaf(w, x6, a6); a7 = fmaf(w, x7, a7); }

  for (int j = 0; j < 4; ++j) {
    const int ldst = wv * 4 + j;
    const int node = b * BDST + ldst;
    if (node >= n) break;
    const uint4 xv = *reinterpret_cast<const uint4*>(xrb + (size_t)node * 256 + u * 16);
    const float xr0 = __uint_as_float(xv.x << 16);
    const float xr1 = __uint_as_float(xv.x & 0xffff0000u);
    const float xr2 = __uint_as_float(xv.y << 16);
    const float xr3 = __uint_as_float(xv.y & 0xffff0000u);
    const float xr4 = __uint_as_float(xv.z << 16);
    const float xr5 = __uint_as_float(xv.z & 0xffff0000u);
    const float xr6 = __uint_as_float(xv.w << 16);
    const float xr7 = __uint_as_float(xv.w & 0xffff0000u);
    const float eB = 0.6f * dB[(size_t)node * 4 + hh];
    const int k0 = lrow[ldst];
    const int deg = lrow[ldst + 1] - k0;   // >= 1 (self-loop)
    const int* ep = elist + k0;

    uint4 V0 = LDE(0), V1 = LDE(1), V2 = LDE(2);
    float d0 = LDA(0), d1 = LDA(1), d2 = LDA(2);
    float s = 0.f;
    float a0 = 0.f, a1 = 0.f, a2 = 0.f, a3 = 0.f;
    float a4 = 0.f, a5 = 0.f, a6 = 0.f, a7 = 0.f;
    const int S = (deg + 3) >> 2;         // steps (4 edges each)
    for (int i = 0; i < S; ++i) {
      uint4 C = V0; float dc = d0;
      V0 = V1; V1 = V2; d0 = d1; d1 = d2;
      V2 = LDE(i + 3); d2 = LDA(i + 3);   // branchless: pad covers over-read
      STEP(C, dc, 4 * i)
    }
    // combine the 4 groups
    s  += __shfl_xor(s, 16);  s  += __shfl_xor(s, 32);
    a0 += __shfl_xor(a0, 16); a0 += __shfl_xor(a0, 32);
    a1 += __shfl_xor(a1, 16); a1 += __shfl_xor(a1, 32);
    a2 += __shfl_xor(a2, 16); a2 += __shfl_xor(a2, 32);
    a3 += __shfl_xor(a3, 16); a3 += __shfl_xor(a3, 32);
    a4 += __shfl_xor(a4, 16); a4 += __shfl_xor(a4, 32);
    a5 += __shfl_xor(a5, 16); a5 += __shfl_xor(a5, 32);
    a6 += __shfl_xor(a6, 16); a6 += __shfl_xor(a6, 32);
    a7 += __shfl_xor(a7, 16); a7 += __shfl_xor(a7, 32);
    float inv = 1.f / (s + 1e-16f);
    if (gi == 0) {
      float* op = out + (size_t)node * 128 + u * 8;
      *reinterpret_cast<float4*>(op) =
          make_float4(a0 * inv, a1 * inv, a2 * inv, a3 * inv);
      *reinterpret_cast<float4*>(op + 4) =
          make_float4(a4 * inv, a5 * inv, a6 * inv, a7 * inv);
    }
  }
  #undef STEP
  #undef LDA
  #undef LDE
}

// ---------------- GraphNorm stats: sorted-batch chunked flush ----------------
__global__ __launch_bounds__(128) void gn_stats(
    const float* __restrict__ out, const float* __restrict__ bias,
    const int* __restrict__ batch, float* __restrict__ gsum,
    float* __restrict__ gsumsq, int* __restrict__ gcnt, int n) {
  const int c = threadIdx.x;
  const int n0 = blockIdx.x * CHUNK;
  const int n1 = min(n0 + CHUNK, n);
  const float bc = bias[c];
  float bsum = 0.f, bsq = 0.f;
  int cnt = 0;
  int curg = batch[n0];
  for (int nid = n0; nid < n1; ++nid) {
    int g = batch[nid];                    // uniform across block -> broadcast
    if (g != curg) {
      atomicAdd(&gsum[curg * 128 + c], bsum);
      atomicAdd(&gsumsq[curg * 128 + c], bsq);
      if (c == 0) atomicAdd(&gcnt[curg], cnt);
      bsum = 0.f; bsq = 0.f; cnt = 0; curg = g;
    }
    float v = out[(size_t)nid * 128 + c] + bc;
    bsum += v; bsq += v * v; ++cnt;
  }
  atomicAdd(&gsum[curg * 128 + c], bsum);
  atomicAdd(&gsumsq[curg * 128 + c], bsq);
  if (c == 0) atomicAdd(&gcnt[curg], cnt);
}

// ---------------- fold GraphNorm into per-(g,c) scale K and shift S ----------------
__global__ __launch_bounds__(128) void gn_prep(
    const float* __restrict__ gsum, const float* __restrict__ gsumsq,
    const int* __restrict__ gcnt, const float* __restrict__ bias,
    const float* __restrict__ msc, const float* __restrict__ w,
    const float* __restrict__ b, float* __restrict__ K, float* __restrict__ S) {
  int g = blockIdx.x, c = threadIdx.x;
  float cnt = (float)max(gcnt[g], 1);
  float mean = gsum[g * 128 + c] / cnt;
  float a = msc[c];
  float var = gsumsq[g * 128 + c] / cnt - mean * mean * (2.f * a - a * a);
  float k = rsqrtf(var + GN_EPS) * w[c];
  K[g * 128 + c] = k;
  S[g * 128 + c] = (bias[c] - mean * a) * k + b[c];
}

// ---------------- normalize + ELU (in place on out), float4 ----------------
__global__ __launch_bounds__(256) void gn_norm(
    float* __restrict__ out, const int* __restrict__ batch,
    const float* __restrict__ K, const float* __restrict__ S, int n) {
  int i = blockIdx.x * 256 + threadIdx.x;     // one thread per 4 channels
  if (i >= n * 32) return;
  int nid = i >> 5, c4 = (i & 31) * 4;
  int g = batch[nid];
  const float4 k4 = *reinterpret_cast<const float4*>(K + g * 128 + c4);
  const float4 s4 = *reinterpret_cast<const float4*>(S + g * 128 + c4);
  float* op = out + (size_t)nid * 128 + c4;
  float4 v = *reinterpret_cast<const float4*>(op);
  v.x = fmaf(v.x, k4.x, s4.x); v.x = (v.x > 0.f) ? v.x : (__expf(v.x) - 1.f);
  v.y = fmaf(v.y, k4.y, s4.y); v.y = (v.y > 0.f) ? v.y : (__expf(v.y) - 1.f);
  v.z = fmaf(v.z, k4.z, s4.z); v.z = (v.z > 0.f) ? v.z : (__expf(v.z) - 1.f);
  v.w = fmaf(v.w, k4.w, s4.w); v.w = (v.w > 0.f) ? v.w : (__expf(v.w) - 1.f);
  *reinterpret_cast<float4*>(op) = v;
}

extern "C" void kernel_launch(void* const* d_in, const int* in_sizes, int n_in,
                              void* d_out, int out_size, void* d_ws, size_t ws_size,
                              hipStream_t stream) {
  const float* x    = (const float*)d_in[0];
  const int*   ei   = (const int*)d_in[1];
  const int*   batch= (const int*)d_in[2];
  const float* Wl   = (const float*)d_in[3];
  const float* Wr   = (const float*)d_in[4];
  const float* att  = (const float*)d_in[5];
  const float* bias = (const float*)d_in[6];
  const float* gw   = (const float*)d_in[7];
  const float* gb   = (const float*)d_in[8];
  const float* gms  = (const float*)d_in[9];
  float* out = (float*)d_out;

  const int n  = in_sizes[0] / 128;
  const int E  = in_sizes[1] / 2;
  const int E2 = E + n;
  const int NBK = (n + BDST - 1) / BDST;
  const int SB = (E2 + 256 * NPT - 1) / (256 * NPT);
  const int GB = (((n + 15) / 16) * 64 + 255) / 256;

  // workspace layout (zero-init region first: gcur|gcnt|gsum|gsumsq)
  char* ws = (char*)d_ws;
  size_t off = 0;
  int*   gcur    = (int*)(ws + off); off += (size_t)((NBK + 63) & ~63) * 4;
  int*   gcnt    = (int*)(ws + off); off += GG * 4;
  float* gsum    = (float*)(ws + off); off += GG * 128 * 4;
  float* gsumsq  = (float*)(ws + off); off += GG * 128 * 4;
  size_t zero_bytes = off;
  int*   ebuf    = (int*)(ws + off); off += (size_t)NBK * SLOT * 4;
  unsigned short* xlb = (unsigned short*)(ws + off); off += (size_t)n * 128 * 2;
  unsigned short* xrb = (unsigned short*)(ws + off); off += (size_t)n * 128 * 2;
  float* dA      = (float*)(ws + off); off += (size_t)((n + 63) & ~63) * 4 * 4;
  float* dB      = (float*)(ws + off); off += (size_t)((n + 63) & ~63) * 4 * 4;
  unsigned short* Bfrag = (unsigned short*)(ws + off); off += 64 * 64 * 8 * 2;
  float* gK      = (float*)(ws + off); off += GG * 128 * 4;
  float* gS      = (float*)(ws + off); off += GG * 128 * 4;

  hipMemsetAsync(ws, 0, zero_bytes, stream);

  wpack<<<16, 256, 0, stream>>>(Wl, Wr, (unsigned short*)Bfrag);

  prep_merged<<<SB + GB, 256, 0, stream>>>(ei, gcur, ebuf, E, E2, NBK, SB,
                                           x, Bfrag, att, xlb, xrb, dA, dB, n);

  fused_aggr<<<NBK, 256, 0, stream>>>(gcur, ebuf, (const unsigned char*)xlb,
                                      (const unsigned char*)xrb, dA, dB,
                                      att, out, n);

  gn_stats<<<(n + CHUNK - 1) / CHUNK, 128, 0, stream>>>(out, bias, batch, gsum, gsumsq, gcnt, n);
  gn_prep<<<GG, 128, 0, stream>>>(gsum, gsumsq, gcnt, bias, gms, gw, gb, gK, gS);

  gn_norm<<<(n * 32 + 255) / 256, 256, 0, stream>>>(out, batch, gK, gS, n);
}